// Round 8
// baseline (21212.541 us; speedup 1.0000x reference)
//
#include <hip/hip_runtime.h>

#define EPS 1e-5f

__device__ __forceinline__ float logsig(float z) {
    return fminf(z, 0.0f) - log1pf(__expf(-fabsf(z)));
}

// One block = one sequence. 256 threads = 4 waves = 4 heads (wave h owns head h,
// full state S[64] per lane: S[k] = state row k, v-col lane).
// PSTRIDE==1  : intra pass (seq over q, SLEN=128); PSTRIDE==128: inter pass (SLEN=256)
// LDS = 155 KB pins occupancy at 1 block/CU regardless of block size. The backend
// caps 512-thread kernels at 128 VGPRs (R4-R7: unmovable; deterministic ~1.5 GB/pass
// spill traffic that also thrashes weights out of L2). 256-thread kernels get a
// 256-VGPR budget (R2/R3) — worst live set here ~130, so everything fits.
template<int SLEN, int PSTRIDE>
__global__ __launch_bounds__(256)
__attribute__((amdgpu_waves_per_eu(1, 1)))
void gla_pass(const float* __restrict__ src, float* __restrict__ out,
              const float* __restrict__ gamma, const float* __restrict__ beta,
              const float* __restrict__ Wq, const float* __restrict__ Wk,
              const float* __restrict__ Wv, const float* __restrict__ Wg1,
              const float* __restrict__ Wg2, const float* __restrict__ Wr,
              const float* __restrict__ gn, const float* __restrict__ Wo,
              const float* __restrict__ ctw, const float* __restrict__ ctb)
{
    constexpr int NC = SLEN / 32;
    constexpr int L  = SLEN - 1;

    __shared__ __align__(16) float sxc[64][36];   // LN'd slab window (33 cols used)
    __shared__ __align__(16) float sxr[64][32];   // raw slab (residual source)
    __shared__ __align__(16) float qf[32][256];   // exp(gc) -> q*Dk^-0.5*exp(gc)
    __shared__ __align__(16) float kf[32][256];   // exp(-gc) -> k*exp(-gc)
    __shared__ __align__(16) float voc[32][256];  // v -> o (normed) -> o*silu(r)
    __shared__ __align__(16) float uni[8832];     // Ats[4][32][36] + gdec[32][132]
    __shared__ __align__(16) float fw1t[32][36];  // (f @ Wg1)^T : fw1t[m][t]
    __shared__ __align__(16) float gprevs[128];   // deconv carry row
    __shared__ __align__(16) float egl[256];      // exp(chunk-total gate)
    __shared__ float sgam[64], sbet[64];
    __shared__ float smu[33], sinv[33];

    float* const Ats  = uni;          // h*1152 + t*36 + s
    float* const gdec = uni + 4608;   // row*132 + c

    const int tid  = threadIdx.x;
    const int lane = tid & 63;
    const int h    = tid >> 6;        // wave id == head id
    const int d    = tid;             // column for projection stages
    const int n    = blockIdx.x;

    int b, fixedoff;
    if constexpr (PSTRIDE == 1) { b = n >> 8; fixedoff = (n & 255) * 128; }
    else                        { b = n >> 7; fixedoff = (n & 127); }
    const int cbase = (b * 64) * 32768 + fixedoff;

    if (tid < 64)  { sgam[tid] = gamma[tid]; sbet[tid] = beta[tid]; }
    if (tid < 128) gprevs[tid] = 0.0f;

    float S[64];                      // full state column (head h, v-col lane)
    #pragma unroll
    for (int k = 0; k < 64; ++k) S[k] = 0.0f;

    const float gnv  = gn[tid];       // gn[h*64 + lane]
    const float bias = ctb[lane];

    for (int ch = 0; ch < NC; ++ch) {
        const int l0 = ch * 32;
        __syncthreads();

        // ---- A: load 33-col slab window (raw copy kept for residual) ----
        for (int idx = tid; idx < 64 * 33; idx += 256) {
            int cc = idx / 33;
            int i  = idx - cc * 33;
            int p  = l0 + i; if (p > SLEN - 1) p = SLEN - 1;
            float x = src[cbase + cc * 32768 + p * PSTRIDE];
            sxc[cc][i] = x;
            if (i < 32) sxr[cc][i] = x;
        }
        __syncthreads();

        // ---- B1: per-column LN stats ----
        if (tid < 33) {
            float s1 = 0.0f, s2 = 0.0f;
            for (int cc = 0; cc < 64; ++cc) { float x = sxc[cc][tid]; s1 += x; s2 += x * x; }
            float mu = s1 * (1.0f / 64.0f);
            float var = s2 * (1.0f / 64.0f) - mu * mu;
            smu[tid]  = mu;
            sinv[tid] = rsqrtf(fmaxf(var, 0.0f) + EPS);
        }
        __syncthreads();
        // ---- B2: normalize in place ----
        for (int idx = tid; idx < 64 * 33; idx += 256) {
            int cc = idx / 33;
            int i  = idx - cc * 33;
            sxc[cc][i] = (sxc[cc][i] - smu[i]) * sinv[i] * sgam[cc] + sbet[cc];
        }
        __syncthreads();

        // ---- gate p1: fw1t[m][t] = (f @ Wg1)^T ----
        {
            const int m = tid & 31, tg = tid >> 5;   // tg in [0,8)
            float a4[4] = {0.0f, 0.0f, 0.0f, 0.0f};
            for (int cc = 0; cc < 64; ++cc) {
                const float w0 = Wg1[(2*cc)*32 + m], w1 = Wg1[(2*cc+1)*32 + m];
                #pragma unroll
                for (int i = 0; i < 4; ++i) {
                    const int t = tg + i * 8;
                    a4[i] += sxc[cc][t] * w0 + sxc[cc][t+1] * w1;
                }
            }
            #pragma unroll
            for (int i = 0; i < 4; ++i) fw1t[m][tg + i * 8] = a4[i];
        }

        // ---- C-v: v projection straight to LDS ----
        {
            float av[32];
            #pragma unroll
            for (int t = 0; t < 32; ++t) av[t] = 0.0f;
            for (int cc = 0; cc < 64; ++cc) {
                float col[33];
                #pragma unroll
                for (int i = 0; i < 8; ++i) {
                    float4 c4 = *(const float4*)&sxc[cc][4 * i];
                    col[4*i] = c4.x; col[4*i+1] = c4.y; col[4*i+2] = c4.z; col[4*i+3] = c4.w;
                }
                col[32] = sxc[cc][32];
                const float wv0 = Wv[(2*cc)*256 + d], wv1 = Wv[(2*cc+1)*256 + d];
                #pragma unroll
                for (int t = 0; t < 32; ++t) av[t] += col[t] * wv0 + col[t+1] * wv1;
            }
            #pragma unroll
            for (int t = 0; t < 32; ++t)
                voc[t][d] = ((l0 + t) < L) ? av[t] : 0.0f;
        }
        __syncthreads();   // fw1t ready

        // ---- gate p2: gc cumsum for col d; stash exp(+-gc) in qf/kf; egl ----
        {
            float acc2[32];
            #pragma unroll
            for (int t = 0; t < 32; ++t) acc2[t] = 0.0f;
            for (int mm = 0; mm < 32; ++mm) {
                const float w = Wg2[mm * 256 + d];
                #pragma unroll
                for (int i = 0; i < 8; ++i) {
                    float4 f4 = *(const float4*)&fw1t[mm][4 * i];
                    acc2[4*i+0] += f4.x * w; acc2[4*i+1] += f4.y * w;
                    acc2[4*i+2] += f4.z * w; acc2[4*i+3] += f4.w * w;
                }
            }
            float r = 0.0f;
            #pragma unroll
            for (int t = 0; t < 32; ++t) {
                if ((l0 + t) < L) r += logsig(acc2[t]) * (1.0f / 32.0f);
                qf[t][d] = __expf(r);
                kf[t][d] = __expf(-r);
            }
            egl[d] = __expf(r);
        }

        // ---- C-q: q projection; same-thread RMW folds exp(gc) ----
        {
            float aq[32];
            #pragma unroll
            for (int t = 0; t < 32; ++t) aq[t] = 0.0f;
            for (int cc = 0; cc < 64; ++cc) {
                float col[33];
                #pragma unroll
                for (int i = 0; i < 8; ++i) {
                    float4 c4 = *(const float4*)&sxc[cc][4 * i];
                    col[4*i] = c4.x; col[4*i+1] = c4.y; col[4*i+2] = c4.z; col[4*i+3] = c4.w;
                }
                col[32] = sxc[cc][32];
                const float wq0 = Wq[(2*cc)*256 + d], wq1 = Wq[(2*cc+1)*256 + d];
                #pragma unroll
                for (int t = 0; t < 32; ++t) aq[t] += col[t] * wq0 + col[t+1] * wq1;
            }
            #pragma unroll
            for (int t = 0; t < 32; ++t) {
                float v = ((l0 + t) < L) ? aq[t] * 0.125f : 0.0f;
                qf[t][d] *= v;
            }
        }

        // ---- C-k: k projection; same-thread RMW folds exp(-gc) ----
        {
            float ak[32];
            #pragma unroll
            for (int t = 0; t < 32; ++t) ak[t] = 0.0f;
            for (int cc = 0; cc < 64; ++cc) {
                float col[33];
                #pragma unroll
                for (int i = 0; i < 8; ++i) {
                    float4 c4 = *(const float4*)&sxc[cc][4 * i];
                    col[4*i] = c4.x; col[4*i+1] = c4.y; col[4*i+2] = c4.z; col[4*i+3] = c4.w;
                }
                col[32] = sxc[cc][32];
                const float wk0 = Wk[(2*cc)*256 + d], wk1 = Wk[(2*cc+1)*256 + d];
                #pragma unroll
                for (int t = 0; t < 32; ++t) ak[t] += col[t] * wk0 + col[t+1] * wk1;
            }
            #pragma unroll
            for (int t = 0; t < 32; ++t) {
                float v = ((l0 + t) < L) ? ak[t] : 0.0f;
                kf[t][d] *= v;
            }
        }
        __syncthreads();   // qf, kf, voc, egl all final

        // ---- F: per-wave (=per-head) attention ----
        const int base = h * 64;
        float vcol[32];
        #pragma unroll
        for (int t = 0; t < 32; ++t) vcol[t] = voc[t][base + lane];

        // F1: triangular scores A[t][s] = sum_d qi[t][d]*ke[s][d]
        for (int pi = lane; pi < 528; pi += 64) {
            float fpi = (float)pi;
            int t = (int)((sqrtf(8.0f * fpi + 1.0f) - 1.0f) * 0.5f);
            if (((t + 1) * (t + 2)) / 2 <= pi) ++t;
            if ((t * (t + 1)) / 2 > pi) --t;
            int s = pi - (t * (t + 1)) / 2;
            float a = 0.0f;
            #pragma unroll
            for (int ii = 0; ii < 16; ++ii) {
                int i = (ii + lane) & 15;          // rotate to spread LDS banks
                float4 q4 = *(const float4*)&qf[t][base + 4 * i];
                float4 k4 = *(const float4*)&kf[s][base + 4 * i];
                a += q4.x*k4.x + q4.y*k4.y + q4.z*k4.z + q4.w*k4.w;
            }
            Ats[h * 1152 + t * 36 + s] = a;
        }
        __syncthreads();   // Ats ready; all vcol snapshots done (voc dead as v)

        // F2: per t: o = o_inter + o_intra, RMS-norm, final o into voc
        #pragma unroll
        for (int t = 0; t < 32; ++t) {
            float ot = 0.0f;
            #pragma unroll
            for (int i = 0; i < 16; ++i) {
                float4 q4 = *(const float4*)&qf[t][base + 4 * i];
                ot += q4.x*S[4*i] + q4.y*S[4*i+1] + q4.z*S[4*i+2] + q4.w*S[4*i+3];
            }
            const float* arow = &Ats[h * 1152 + t * 36];
            #pragma unroll
            for (int s4 = 0; s4 + 4 <= t + 1; s4 += 4) {
                float4 a4 = *(const float4*)&arow[s4];
                ot += a4.x*vcol[s4] + a4.y*vcol[s4+1] + a4.z*vcol[s4+2] + a4.w*vcol[s4+3];
            }
            #pragma unroll
            for (int s = (t + 1) & ~3; s <= t; ++s) ot += arow[s] * vcol[s];
            float ss = ot * ot;
            #pragma unroll
            for (int off = 32; off > 0; off >>= 1) ss += __shfl_xor(ss, off, 64);
            voc[t][base + lane] = ot * rsqrtf(ss * (1.0f / 64.0f) + EPS) * gnv;
        }

        // F4: S = exp(gl) * (S + ke^T v), float4 strips (uses pre-update S? no:
        // F2 used S already; safe to update now, same thread order)
        #pragma unroll
        for (int i = 0; i < 16; ++i) {
            float s0 = 0.0f, s1 = 0.0f, s2 = 0.0f, s3 = 0.0f;
            #pragma unroll
            for (int t = 0; t < 32; ++t) {
                float4 k4 = *(const float4*)&kf[t][base + 4 * i];
                const float vt = vcol[t];
                s0 += k4.x * vt; s1 += k4.y * vt; s2 += k4.z * vt; s3 += k4.w * vt;
            }
            float4 e4 = *(const float4*)&egl[base + 4 * i];
            S[4*i+0] = e4.x * (S[4*i+0] + s0);
            S[4*i+1] = e4.y * (S[4*i+1] + s1);
            S[4*i+2] = e4.z * (S[4*i+2] + s2);
            S[4*i+3] = e4.w * (S[4*i+3] + s3);
        }
        __syncthreads();   // final o in voc

        // ---- G: r = f @ Wr ; voc *= silu(r) ----
        {
            float ar[32];
            #pragma unroll
            for (int t = 0; t < 32; ++t) ar[t] = 0.0f;
            for (int cc = 0; cc < 64; ++cc) {
                float col[33];
                #pragma unroll
                for (int i = 0; i < 8; ++i) {
                    float4 c4 = *(const float4*)&sxc[cc][4 * i];
                    col[4*i] = c4.x; col[4*i+1] = c4.y; col[4*i+2] = c4.z; col[4*i+3] = c4.w;
                }
                col[32] = sxc[cc][32];
                const float w0 = Wr[(2*cc)*256 + d], w1 = Wr[(2*cc+1)*256 + d];
                #pragma unroll
                for (int t = 0; t < 32; ++t) ar[t] += col[t] * w0 + col[t+1] * w1;
            }
            #pragma unroll
            for (int t = 0; t < 32; ++t) {
                const float r = ar[t];
                voc[t][d] *= r / (1.0f + __expf(-r));
            }
        }
        __syncthreads();

        // ---- H: gdec = oc @ Wo ; thread = (m in [0,128), 16 rows) ----
        {
            const int m  = tid & 127;
            const int tg = tid >> 7;          // rows 0..15 / 16..31
            float acc[16];
            #pragma unroll
            for (int i = 0; i < 16; ++i) acc[i] = 0.0f;
            for (int j = 0; j < 256; j += 4) {
                const float w0 = Wo[(j+0)*128 + m];
                const float w1 = Wo[(j+1)*128 + m];
                const float w2 = Wo[(j+2)*128 + m];
                const float w3 = Wo[(j+3)*128 + m];
                #pragma unroll
                for (int i = 0; i < 16; ++i) {
                    float4 o4 = *(const float4*)&voc[tg * 16 + i][j];
                    acc[i] += o4.x*w0 + o4.y*w1 + o4.z*w2 + o4.w*w3;
                }
            }
            #pragma unroll
            for (int i = 0; i < 16; ++i) gdec[(tg * 16 + i) * 132 + m] = acc[i];
        }
        __syncthreads();

        // ---- I: deconv1d (K=2) + bias + residual (from sxr) + store ----
        {
            const int o  = lane;
            const int pg = h;                 // 0..3 -> rows pg*8..+7
            const float2* ctw2 = (const float2*)ctw;   // [cin][o] -> (w_k0, w_k1)
            float acc8[8];
            #pragma unroll
            for (int i = 0; i < 8; ++i) acc8[i] = 0.0f;
            for (int c4 = 0; c4 < 128; c4 += 4) {
                float2 w0 = ctw2[(c4+0)*64 + o];
                float2 w1 = ctw2[(c4+1)*64 + o];
                float2 w2 = ctw2[(c4+2)*64 + o];
                float2 w3 = ctw2[(c4+3)*64 + o];
                float4 r[9];   // rows pg*8-1 .. pg*8+7, cols c4..c4+3
                r[0] = (pg == 0) ? *(const float4*)&gprevs[c4]
                                 : *(const float4*)&gdec[(pg*8 - 1) * 132 + c4];
                #pragma unroll
                for (int j = 1; j < 9; ++j)
                    r[j] = *(const float4*)&gdec[(pg*8 + j - 1) * 132 + c4];
                #pragma unroll
                for (int i = 0; i < 8; ++i) {
                    acc8[i] += r[i+1].x*w0.x + r[i].x*w0.y
                             + r[i+1].y*w1.x + r[i].y*w1.y
                             + r[i+1].z*w2.x + r[i].z*w2.y
                             + r[i+1].w*w3.x + r[i].w*w3.y;
                }
            }
            #pragma unroll
            for (int i = 0; i < 8; ++i) {
                const int tl = pg * 8 + i;
                const int oi = cbase + o * 32768 + (l0 + tl) * PSTRIDE;
                out[oi] = acc8[i] + bias + sxr[o][tl];
            }
        }
        __syncthreads();
        if (tid < 128) gprevs[tid] = gdec[31 * 132 + tid];
    }
}

extern "C" void kernel_launch(void* const* d_in, const int* in_sizes, int n_in,
                              void* d_out, int out_size, void* d_ws, size_t ws_size,
                              hipStream_t stream)
{
    const float* x = (const float*)d_in[0];
    float* y = (float*)d_ws;     // intra output: 4*64*256*128 fp32
    float* z = (float*)d_out;

    gla_pass<128, 1><<<dim3(1024), dim3(256), 0, stream>>>(
        x, y,
        (const float*)d_in[2],  (const float*)d_in[3],  (const float*)d_in[4],
        (const float*)d_in[5],  (const float*)d_in[6],  (const float*)d_in[7],
        (const float*)d_in[8],  (const float*)d_in[9],  (const float*)d_in[10],
        (const float*)d_in[11], (const float*)d_in[12], (const float*)d_in[13]);

    gla_pass<256, 128><<<dim3(512), dim3(256), 0, stream>>>(
        y, z,
        (const float*)d_in[14], (const float*)d_in[15], (const float*)d_in[16],
        (const float*)d_in[17], (const float*)d_in[18], (const float*)d_in[19],
        (const float*)d_in[20], (const float*)d_in[21], (const float*)d_in[22],
        (const float*)d_in[23], (const float*)d_in[24], (const float*)d_in[25]);
}

// Round 9
// 9409.089 us; speedup vs baseline: 2.2545x; 2.2545x over previous
//
#include <hip/hip_runtime.h>

#define EPS 1e-5f

__device__ __forceinline__ float logsig(float z) {
    return fminf(z, 0.0f) - log1pf(__expf(-fabsf(z)));
}

// One block = one sequence. 1024 threads = 16 waves.
// Config map (R2-R8): VGPR cap is 256 for 256t, 128 for 512t/1024t blocks; both
// 256t ([32] arrays, S[64]) and 512t ([16] arrays + S[32]) overflow their cap ->
// deterministic scratch spill traffic dominates (3.5-15 GB/pass vs 33 MB logical).
// 1024t shrinks per-thread arrays to [8]; state waves keep R6's proven S[32]+
// vcol[32] (~85 peak live) -> everything fits under 128 with pipelining slack.
// Waves 0..7 = state waves (h=wv&3, kh=wv>>2, S[32] = k-rows kh*32..+31).
// Waves 8..15 help in parallel stages (projections, F1 scores, G/H/I).
// PSTRIDE==1: intra pass (SLEN=128); PSTRIDE==128: inter pass (SLEN=256).
template<int SLEN, int PSTRIDE>
__global__ __launch_bounds__(1024)
void gla_pass(const float* __restrict__ src, float* __restrict__ out,
              const float* __restrict__ gamma, const float* __restrict__ beta,
              const float* __restrict__ Wq, const float* __restrict__ Wk,
              const float* __restrict__ Wv, const float* __restrict__ Wg1,
              const float* __restrict__ Wg2, const float* __restrict__ Wr,
              const float* __restrict__ gn, const float* __restrict__ Wo,
              const float* __restrict__ ctw, const float* __restrict__ ctb)
{
    constexpr int NC = SLEN / 32;
    constexpr int L  = SLEN - 1;

    __shared__ __align__(16) float sxc[64][36];   // LN'd slab window (33 cols used)
    __shared__ __align__(16) float sxr[64][32];   // raw slab (residual source)
    __shared__ __align__(16) float qf[32][256];   // q*Dk^-0.5*exp(gc)
    __shared__ __align__(16) float kf[32][256];   // k*exp(-gc)
    __shared__ __align__(16) float voc[32][256];  // v -> oe1 partial -> o -> o*silu(r)
    __shared__ __align__(16) float uni[8832];     // Ats[4][32][36] + gdec[32][132]
    __shared__ __align__(16) float fw1t[32][36];  // (f @ Wg1)^T : fw1t[m][t]
    __shared__ __align__(16) float gprevs[128];   // deconv carry row
    __shared__ __align__(16) float egl[256];      // exp(chunk-total gate)
    __shared__ float sgam[64], sbet[64];
    __shared__ float smu[33], sinv[33];

    float* const Ats  = uni;          // h*1152 + t*36 + s
    float* const gdec = uni + 4608;   // row*132 + c  (H/I stages)
    float* const gq   = uni + 4608;   // [4][256] gate-cumsum quarter totals (gate stage)

    const int tid  = threadIdx.x;
    const int lane = tid & 63;
    const int wv   = tid >> 6;        // 0..15
    const int h    = wv & 3;          // head (state waves 0..7; also F1 head)
    const int kh   = wv >> 2;         // 0/1 for state waves
    const int dd   = tid & 255;       // projection column
    const int tq   = tid >> 8;        // 0..3 -> rows tq*8..tq*8+7
    const int n    = blockIdx.x;

    int b, fixedoff;
    if constexpr (PSTRIDE == 1) { b = n >> 8; fixedoff = (n & 255) * 128; }
    else                        { b = n >> 7; fixedoff = (n & 127); }
    const int cbase = (b * 64) * 32768 + fixedoff;

    if (tid < 64)  { sgam[tid] = gamma[tid]; sbet[tid] = beta[tid]; }
    if (tid < 128) gprevs[tid] = 0.0f;

    float S[32];                      // state half (waves 0..7 only; junk elsewhere)
    #pragma unroll
    for (int k = 0; k < 32; ++k) S[k] = 0.0f;

    const float gnv  = gn[h * 64 + lane];
    const float bias = ctb[lane];

    for (int ch = 0; ch < NC; ++ch) {
        const int l0 = ch * 32;
        __syncthreads();

        // ---- A: load 33-col slab window (raw copy kept for residual) ----
        for (int idx = tid; idx < 64 * 33; idx += 1024) {
            int cc = idx / 33;
            int i  = idx - cc * 33;
            int p  = l0 + i; if (p > SLEN - 1) p = SLEN - 1;
            float x = src[cbase + cc * 32768 + p * PSTRIDE];
            sxc[cc][i] = x;
            if (i < 32) sxr[cc][i] = x;
        }
        __syncthreads();

        // ---- B1: per-column LN stats ----
        if (tid < 33) {
            float s1 = 0.0f, s2 = 0.0f;
            for (int cc = 0; cc < 64; ++cc) { float x = sxc[cc][tid]; s1 += x; s2 += x * x; }
            float mu = s1 * (1.0f / 64.0f);
            float var = s2 * (1.0f / 64.0f) - mu * mu;
            smu[tid]  = mu;
            sinv[tid] = rsqrtf(fmaxf(var, 0.0f) + EPS);
        }
        __syncthreads();
        // ---- B2: normalize in place ----
        for (int idx = tid; idx < 64 * 33; idx += 1024) {
            int cc = idx / 33;
            int i  = idx - cc * 33;
            sxc[cc][i] = (sxc[cc][i] - smu[i]) * sinv[i] * sgam[cc] + sbet[cc];
        }
        __syncthreads();

        // ---- gate p1: fw1t[m][t], one output per thread ----
        {
            const int m = tid & 31, t1 = tid >> 5;    // t1 in [0,32)
            float a = 0.0f;
            for (int cc = 0; cc < 64; ++cc)
                a += sxc[cc][t1] * Wg1[(2*cc)*32 + m] + sxc[cc][t1+1] * Wg1[(2*cc+1)*32 + m];
            fw1t[m][t1] = a;
        }

        // ---- C: fused q,k,v projections; thread = (col dd, t-quarter tq) ----
        const int t0 = tq * 8;
        float aq[8], ak[8];
        {
            float av[8];
            #pragma unroll
            for (int t = 0; t < 8; ++t) { aq[t] = 0.0f; ak[t] = 0.0f; av[t] = 0.0f; }
            for (int cc = 0; cc < 64; ++cc) {
                float col[9];
                float4 c4a = *(const float4*)&sxc[cc][t0];
                float4 c4b = *(const float4*)&sxc[cc][t0 + 4];
                col[0]=c4a.x; col[1]=c4a.y; col[2]=c4a.z; col[3]=c4a.w;
                col[4]=c4b.x; col[5]=c4b.y; col[6]=c4b.z; col[7]=c4b.w;
                col[8]=sxc[cc][t0 + 8];
                const float wq0 = Wq[(2*cc)*256 + dd], wq1 = Wq[(2*cc+1)*256 + dd];
                const float wk0 = Wk[(2*cc)*256 + dd], wk1 = Wk[(2*cc+1)*256 + dd];
                const float wv0 = Wv[(2*cc)*256 + dd], wv1 = Wv[(2*cc+1)*256 + dd];
                #pragma unroll
                for (int t = 0; t < 8; ++t) {
                    aq[t] += col[t] * wq0 + col[t+1] * wq1;
                    ak[t] += col[t] * wk0 + col[t+1] * wk1;
                    av[t] += col[t] * wv0 + col[t+1] * wv1;
                }
            }
            #pragma unroll
            for (int t = 0; t < 8; ++t)
                voc[t0 + t][dd] = ((l0 + t0 + t) < L) ? av[t] : 0.0f;
        }
        __syncthreads();   // fw1t ready (voc staged)

        // ---- gate p2a: gk quarter-cumsum; write quarter total ----
        float lrun[8];
        {
            float acc2[8];
            #pragma unroll
            for (int t = 0; t < 8; ++t) acc2[t] = 0.0f;
            for (int mm = 0; mm < 32; ++mm) {
                const float w = Wg2[mm * 256 + dd];
                float4 f4a = *(const float4*)&fw1t[mm][t0];
                float4 f4b = *(const float4*)&fw1t[mm][t0 + 4];
                acc2[0] += f4a.x * w; acc2[1] += f4a.y * w;
                acc2[2] += f4a.z * w; acc2[3] += f4a.w * w;
                acc2[4] += f4b.x * w; acc2[5] += f4b.y * w;
                acc2[6] += f4b.z * w; acc2[7] += f4b.w * w;
            }
            float r = 0.0f;
            #pragma unroll
            for (int t = 0; t < 8; ++t) {
                if ((l0 + t0 + t) < L) r += logsig(acc2[t]) * (1.0f / 32.0f);
                lrun[t] = r;
            }
            gq[tq * 256 + dd] = r;
        }
        __syncthreads();   // gq ready

        // ---- gate p2b: prefix carry, fold exp(+-gc) into aq/ak, store qf/kf ----
        {
            float c = 0.0f;
            #pragma unroll
            for (int j = 0; j < 3; ++j) if (j < tq) c += gq[j * 256 + dd];
            #pragma unroll
            for (int t = 0; t < 8; ++t) {
                bool valid = (l0 + t0 + t) < L;
                float run = c + lrun[t];
                qf[t0 + t][dd] = valid ? aq[t] * 0.125f * __expf(run) : 0.0f;
                kf[t0 + t][dd] = valid ? ak[t] * __expf(-run) : 0.0f;
            }
            if (tq == 3) egl[dd] = __expf(c + lrun[7]);
        }
        __syncthreads();   // qf/kf/egl/voc all final

        // ---- F: attention ----
        const int base = h * 64;
        float vcol[32];
        if (wv < 8) {      // state waves snapshot v column
            #pragma unroll
            for (int t = 0; t < 32; ++t) vcol[t] = voc[t][base + lane];
        }

        // F1: triangular scores, all 16 waves (4 per head), 256 lanes/head
        {
            const int fq = wv >> 2;   // 0..3
            for (int pi = lane + 64 * fq; pi < 528; pi += 256) {
                float fpi = (float)pi;
                int t = (int)((sqrtf(8.0f * fpi + 1.0f) - 1.0f) * 0.5f);
                if (((t + 1) * (t + 2)) / 2 <= pi) ++t;
                if ((t * (t + 1)) / 2 > pi) --t;
                int s = pi - (t * (t + 1)) / 2;
                float a = 0.0f;
                #pragma unroll
                for (int ii = 0; ii < 16; ++ii) {
                    int i = (ii + lane) & 15;
                    float4 q4 = *(const float4*)&qf[t][base + 4 * i];
                    float4 k4 = *(const float4*)&kf[s][base + 4 * i];
                    a += q4.x*k4.x + q4.y*k4.y + q4.z*k4.z + q4.w*k4.w;
                }
                Ats[h * 1152 + t * 36 + s] = a;
            }
        }
        __syncthreads();   // Ats ready; voc dead as v

        // F2a: kh1 state waves write o_inter partial (pre-update S rows 32..63)
        if (wv >= 4 && wv < 8) {
            #pragma unroll
            for (int t = 0; t < 32; ++t) {
                float oe = 0.0f;
                #pragma unroll
                for (int i = 0; i < 8; ++i) {
                    float4 q4 = *(const float4*)&qf[t][base + 32 + 4 * i];
                    oe += q4.x*S[4*i] + q4.y*S[4*i+1] + q4.z*S[4*i+2] + q4.w*S[4*i+3];
                }
                voc[t][base + lane] = oe;
            }
        }
        __syncthreads();   // oe1 partials in voc

        if (wv < 4) {
            // F2b (kh0): o = oe0 + oe1 + o_intra, RMS-norm, final o into voc
            #pragma unroll
            for (int t = 0; t < 32; ++t) {
                float ot = voc[t][base + lane];
                #pragma unroll
                for (int i = 0; i < 8; ++i) {
                    float4 q4 = *(const float4*)&qf[t][base + 4 * i];
                    ot += q4.x*S[4*i] + q4.y*S[4*i+1] + q4.z*S[4*i+2] + q4.w*S[4*i+3];
                }
                const float* arow = &Ats[h * 1152 + t * 36];
                #pragma unroll
                for (int s4 = 0; s4 + 4 <= t + 1; s4 += 4) {
                    float4 a4 = *(const float4*)&arow[s4];
                    ot += a4.x*vcol[s4] + a4.y*vcol[s4+1] + a4.z*vcol[s4+2] + a4.w*vcol[s4+3];
                }
                #pragma unroll
                for (int s = (t + 1) & ~3; s <= t; ++s) ot += arow[s] * vcol[s];
                float ss = ot * ot;
                #pragma unroll
                for (int off = 32; off > 0; off >>= 1) ss += __shfl_xor(ss, off, 64);
                voc[t][base + lane] = ot * rsqrtf(ss * (1.0f / 64.0f) + EPS) * gnv;
            }
        } else if (wv < 8) {
            // kh1: F4 state update rows 32..63 (overlaps kh0's F2b)
            const int kb = base + 32;
            #pragma unroll
            for (int i = 0; i < 8; ++i) {
                float s0 = 0.0f, s1 = 0.0f, s2 = 0.0f, s3 = 0.0f;
                #pragma unroll
                for (int t = 0; t < 32; ++t) {
                    float4 k4 = *(const float4*)&kf[t][kb + 4 * i];
                    const float vt = vcol[t];
                    s0 += k4.x * vt; s1 += k4.y * vt; s2 += k4.z * vt; s3 += k4.w * vt;
                }
                float4 e4 = *(const float4*)&egl[kb + 4 * i];
                S[4*i+0] = e4.x * (S[4*i+0] + s0);
                S[4*i+1] = e4.y * (S[4*i+1] + s1);
                S[4*i+2] = e4.z * (S[4*i+2] + s2);
                S[4*i+3] = e4.w * (S[4*i+3] + s3);
            }
        }
        __syncthreads();   // final o in voc

        if (wv < 4) {
            // kh0: F4 state update rows 0..31 (overlaps start of G)
            #pragma unroll
            for (int i = 0; i < 8; ++i) {
                float s0 = 0.0f, s1 = 0.0f, s2 = 0.0f, s3 = 0.0f;
                #pragma unroll
                for (int t = 0; t < 32; ++t) {
                    float4 k4 = *(const float4*)&kf[t][base + 4 * i];
                    const float vt = vcol[t];
                    s0 += k4.x * vt; s1 += k4.y * vt; s2 += k4.z * vt; s3 += k4.w * vt;
                }
                float4 e4 = *(const float4*)&egl[base + 4 * i];
                S[4*i+0] = e4.x * (S[4*i+0] + s0);
                S[4*i+1] = e4.y * (S[4*i+1] + s1);
                S[4*i+2] = e4.z * (S[4*i+2] + s2);
                S[4*i+3] = e4.w * (S[4*i+3] + s3);
            }
        }

        // ---- G: r = f @ Wr ; voc *= silu(r) ----
        {
            float ar[8];
            #pragma unroll
            for (int t = 0; t < 8; ++t) ar[t] = 0.0f;
            for (int cc = 0; cc < 64; ++cc) {
                float col[9];
                float4 c4a = *(const float4*)&sxc[cc][t0];
                float4 c4b = *(const float4*)&sxc[cc][t0 + 4];
                col[0]=c4a.x; col[1]=c4a.y; col[2]=c4a.z; col[3]=c4a.w;
                col[4]=c4b.x; col[5]=c4b.y; col[6]=c4b.z; col[7]=c4b.w;
                col[8]=sxc[cc][t0 + 8];
                const float w0 = Wr[(2*cc)*256 + dd], w1 = Wr[(2*cc+1)*256 + dd];
                #pragma unroll
                for (int t = 0; t < 8; ++t) ar[t] += col[t] * w0 + col[t+1] * w1;
            }
            #pragma unroll
            for (int t = 0; t < 8; ++t) {
                const float r = ar[t];
                voc[t0 + t][dd] *= r / (1.0f + __expf(-r));
            }
        }
        __syncthreads();

        // ---- H: gdec = oc @ Wo ; thread = (m in [0,128), 4 rows) ----
        {
            const int m  = tid & 127;
            const int tg = tid >> 7;          // 0..7 -> rows tg*4..+3
            float acc[4] = {0, 0, 0, 0};
            for (int j = 0; j < 256; j += 4) {
                const float w0 = Wo[(j+0)*128 + m];
                const float w1 = Wo[(j+1)*128 + m];
                const float w2 = Wo[(j+2)*128 + m];
                const float w3 = Wo[(j+3)*128 + m];
                #pragma unroll
                for (int i = 0; i < 4; ++i) {
                    float4 o4 = *(const float4*)&voc[tg * 4 + i][j];
                    acc[i] += o4.x*w0 + o4.y*w1 + o4.z*w2 + o4.w*w3;
                }
            }
            #pragma unroll
            for (int i = 0; i < 4; ++i) gdec[(tg * 4 + i) * 132 + m] = acc[i];
        }
        __syncthreads();

        // ---- I: deconv1d (K=2) + bias + residual (from sxr) + store; 2 rows/thread ----
        {
            const int o  = lane;
            const int pg = wv;                 // 0..15 -> rows pg*2, pg*2+1
            const float2* ctw2 = (const float2*)ctw;   // [cin][o] -> (w_k0, w_k1)
            float a0 = 0.0f, a1 = 0.0f;
            for (int c4 = 0; c4 < 128; c4 += 4) {
                float2 w0 = ctw2[(c4+0)*64 + o];
                float2 w1 = ctw2[(c4+1)*64 + o];
                float2 w2 = ctw2[(c4+2)*64 + o];
                float2 w3 = ctw2[(c4+3)*64 + o];
                float4 rm = (pg == 0) ? *(const float4*)&gprevs[c4]
                                      : *(const float4*)&gdec[(pg*2 - 1) * 132 + c4];
                float4 r0 = *(const float4*)&gdec[(pg*2 + 0) * 132 + c4];
                float4 r1 = *(const float4*)&gdec[(pg*2 + 1) * 132 + c4];
                a0 += r0.x*w0.x + rm.x*w0.y + r0.y*w1.x + rm.y*w1.y
                    + r0.z*w2.x + rm.z*w2.y + r0.w*w3.x + rm.w*w3.y;
                a1 += r1.x*w0.x + r0.x*w0.y + r1.y*w1.x + r0.y*w1.y
                    + r1.z*w2.x + r0.z*w2.y + r1.w*w3.x + r0.w*w3.y;
            }
            const int tl0 = pg * 2;
            const int oi0 = cbase + o * 32768 + (l0 + tl0) * PSTRIDE;
            out[oi0]           = a0 + bias + sxr[o][tl0];
            out[oi0 + PSTRIDE] = a1 + bias + sxr[o][tl0 + 1];
        }
        __syncthreads();
        if (tid < 128) gprevs[tid] = gdec[31 * 132 + tid];
    }
}

extern "C" void kernel_launch(void* const* d_in, const int* in_sizes, int n_in,
                              void* d_out, int out_size, void* d_ws, size_t ws_size,
                              hipStream_t stream)
{
    const float* x = (const float*)d_in[0];
    float* y = (float*)d_ws;     // intra output: 4*64*256*128 fp32
    float* z = (float*)d_out;

    gla_pass<128, 1><<<dim3(1024), dim3(1024), 0, stream>>>(
        x, y,
        (const float*)d_in[2],  (const float*)d_in[3],  (const float*)d_in[4],
        (const float*)d_in[5],  (const float*)d_in[6],  (const float*)d_in[7],
        (const float*)d_in[8],  (const float*)d_in[9],  (const float*)d_in[10],
        (const float*)d_in[11], (const float*)d_in[12], (const float*)d_in[13]);

    gla_pass<256, 128><<<dim3(512), dim3(1024), 0, stream>>>(
        y, z,
        (const float*)d_in[14], (const float*)d_in[15], (const float*)d_in[16],
        (const float*)d_in[17], (const float*)d_in[18], (const float*)d_in[19],
        (const float*)d_in[20], (const float*)d_in[21], (const float*)d_in[22],
        (const float*)d_in[23], (const float*)d_in[24], (const float*)d_in[25]);
}